// Round 8
// baseline (254.688 us; speedup 1.0000x reference)
//
#include <hip/hip_runtime.h>
#include <math.h>

// ProtoLoss: loss = mean_n( -2*sim[n,fam[n]] + logsumexp_f(4*sim[n,f]) )
// sim = (e.p)/(||e||*||p||) -- scale-invariant in p: count division cancels,
// p_hat = raw_sum/||raw_sum||. N=262144, D=128, F=64.
// A) ONE read of E: segment raw sums (wave-private LDS acc, 4-row dedup ->
//    batched DS, r7 fix) + e_hat = e/||e|| packed bf16 out (67 MB -> L3),
//    with batch-ahead global prefetch (1 wave/SIMD -> latency must be hidden
//    in-wave).
// B) 64 blocks: reduce 256 partials -> normalize -> protoB bf16 (unit norm).
// C) bf16 MFMA 128x64 K=128 on unit-norm operands (sim = acc directly),
//    lean lse epilogue, 1 atomic per block. e_hat read is L3-hot.

#define D_DIM 128
#define F_NUM 64
#define AROWS 65                      // 64 fams + dummy row for dedup'd slots
#define AST (AROWS * D_DIM)           // 8320 floats per wave-private acc

typedef __attribute__((ext_vector_type(8))) short short8;
typedef __attribute__((ext_vector_type(4))) float f32x4;

static __device__ __forceinline__ unsigned short f2bf(float x) {
  union { float f; unsigned u; } v; v.f = x;
  unsigned r = v.u + 0x7FFFu + ((v.u >> 16) & 1u);   // RNE
  return (unsigned short)(r >> 16);
}

// ---------------- Pass A -----------------------------------------------------
// grid N/1024 x 256 thr (4 waves = 4 replicas). Full row per wave-instr:
// lane l holds dims 2l,2l+1 (float2, 512B coalesced). 16-row batches with
// next-batch prefetch. Per batch: 16x(norm-reduce + ehat store), then 4
// subbatches of 4 rows with wave-uniform family dedup -> 4 independent
// ds_read_b64/add/ds_write_b64 (no per-row RAW round-trip).
__global__ __launch_bounds__(256) void pass_a(
    const float* __restrict__ emb, const int* __restrict__ fam,
    float* __restrict__ psum, unsigned int* __restrict__ ehat)
{
  __shared__ float acc[4 * AST];      // 133120 B; wave w owns [w*AST, +AST)
  int t = threadIdx.x;
  float4 z = make_float4(0.f, 0.f, 0.f, 0.f);
  float4* a4 = (float4*)acc;
  for (int i = t; i < AST; i += 256) a4[i] = z;   // 4*AST floats = AST float4s
  __syncthreads();

  int w = t >> 6, l = t & 63;
  float* my = acc + w * AST;
  int base = __builtin_amdgcn_readfirstlane(blockIdx.x * 1024 + w * 256);
  const float2* e2 = (const float2*)emb;

  float2 v[16]; int f[16];
  #pragma unroll
  for (int j = 0; j < 16; ++j) {                  // prime the pipeline
    v[j] = e2[(size_t)(base + j) * 64 + l];
    f[j] = fam[base + j];                         // uniform -> s_load
  }

  #pragma unroll 1
  for (int b = 0; b < 16; ++b) {
    float2 vn[16]; int fn[16];
    if (b < 15) {
      int nb = base + (b + 1) * 16;
      #pragma unroll
      for (int j = 0; j < 16; ++j) {              // next batch in flight
        vn[j] = e2[(size_t)(nb + j) * 64 + l];
        fn[j] = fam[nb + j];
      }
    }

    // norms + e_hat for current batch (before dedup mutates v[])
    #pragma unroll
    for (int j = 0; j < 16; ++j) {
      float x = v[j].x, y = v[j].y;
      float nq = x * x + y * y;
      nq += __shfl_xor(nq, 1);  nq += __shfl_xor(nq, 2);  nq += __shfl_xor(nq, 4);
      nq += __shfl_xor(nq, 8);  nq += __shfl_xor(nq, 16); nq += __shfl_xor(nq, 32);
      float inv = rsqrtf(fmaxf(nq, 1e-20f));
      ehat[(size_t)(base + b * 16 + j) * 64 + l] =
          ((unsigned)f2bf(y * inv) << 16) | f2bf(x * inv);
    }

    // dedup + DS accumulate, subbatches of 4
    #pragma unroll
    for (int s4 = 0; s4 < 4; ++s4) {
      int jj = s4 * 4;
      #pragma unroll
      for (int k = 1; k < 4; ++k) {
        #pragma unroll
        for (int j = 0; j < k; ++j) {
          if (f[jj + j] == f[jj + k]) {           // wave-uniform compare
            v[jj + j].x += v[jj + k].x;
            v[jj + j].y += v[jj + k].y;
            f[jj + k] = 64;                       // dummy row
          }
        }
      }
      float2 cur[4];
      #pragma unroll
      for (int j = 0; j < 4; ++j)                 // distinct addrs -> batched
        cur[j] = *(float2*)&my[f[jj + j] * D_DIM + 2 * l];
      #pragma unroll
      for (int j = 0; j < 4; ++j) {
        cur[j].x += v[jj + j].x; cur[j].y += v[jj + j].y;
      }
      #pragma unroll
      for (int j = 0; j < 4; ++j)
        *(float2*)&my[f[jj + j] * D_DIM + 2 * l] = cur[j];
    }

    #pragma unroll
    for (int j = 0; j < 16; ++j) { v[j] = vn[j]; f[j] = fn[j]; }
  }
  __syncthreads();

  // merge 4 replicas -> block-private psum slot (streaming dwordx4 stores)
  float4* out4 = (float4*)(psum + (size_t)blockIdx.x * (F_NUM * D_DIM));
  #pragma unroll
  for (int k = 0; k < 8; ++k) {
    int idx4 = t + k * 256;                       // 0..2047 float4s of [64][128]
    int ff = idx4 >> 5, c4 = idx4 & 31;
    float4 r = z;
    #pragma unroll
    for (int rp = 0; rp < 4; ++rp) {
      float4 a = *(const float4*)&acc[rp * AST + ff * D_DIM + c4 * 4];
      r.x += a.x; r.y += a.y; r.z += a.z; r.w += a.w;
    }
    out4[idx4] = r;
  }
}

// ---------------- Pass B -----------------------------------------------------
// 64 blocks (one per family) x 256 thr: reduce 256 partials over [128] dims,
// normalize to unit length, write bf16.
__global__ __launch_bounds__(256) void pass_b(
    const float* __restrict__ psum, unsigned short* __restrict__ protoB,
    int nPart)
{
  __shared__ float red[256];
  __shared__ float prot[128];
  __shared__ float nrm[2];
  int fb = blockIdx.x, t = threadIdx.x;
  int d = t & 127, h = t >> 7;                    // h in {0,1}
  int per = nPart >> 1;
  float s = 0.f;
  #pragma unroll 8
  for (int i = 0; i < per; ++i)
    s += psum[(size_t)(h + 2 * i) * (F_NUM * D_DIM) + fb * D_DIM + d];
  red[t] = s;
  __syncthreads();
  if (t < 128) {
    float p = red[t] + red[t + 128];
    prot[t] = p;
    float q = p * p;
    q += __shfl_xor(q, 1);  q += __shfl_xor(q, 2);  q += __shfl_xor(q, 4);
    q += __shfl_xor(q, 8);  q += __shfl_xor(q, 16); q += __shfl_xor(q, 32);
    if ((t & 63) == 0) nrm[t >> 6] = q;
  }
  __syncthreads();
  if (t < 128) {
    float inv = rsqrtf(fmaxf(nrm[0] + nrm[1], 1e-24f));  // empty fam -> sim 0
    protoB[fb * D_DIM + t] = f2bf(prot[t] * inv);
  }
}

// ---------------- Pass C -----------------------------------------------------
// N/128 blocks x 256 thr. e_hat bf16 (L3-hot) + unit protos -> sim = MFMA acc.
// Tile 128 rows x 64 fams, K=128, MFMA 16x16x32. LDS pad 136 -> b128 clean.
__global__ __launch_bounds__(256) void pass_c(
    const unsigned short* __restrict__ ehat, const int* __restrict__ fam,
    const unsigned short* __restrict__ protoB,
    float* __restrict__ out, float invN)
{
  __shared__ __align__(16) unsigned short sA[128 * 136];   // 34816 B
  __shared__ __align__(16) unsigned short sB[F_NUM * 136]; // 17408 B
  __shared__ int   sFam[128];
  __shared__ float sWp[4];

  int t = threadIdx.x;
  int R0 = blockIdx.x * 128;
  const short8* srcA = (const short8*)ehat;
  const short8* srcB = (const short8*)protoB;

  #pragma unroll
  for (int it = 0; it < 8; ++it) {
    int idx = it * 256 + t;                       // 0..2047 16B chunks
    int row = idx >> 4, c8 = idx & 15;            // 4 rows/wave-instr = 1 KB
    *(short8*)&sA[row * 136 + c8 * 8] = srcA[(size_t)(R0 + row) * 16 + c8];
  }
  #pragma unroll
  for (int it = 0; it < 4; ++it) {
    int idx = it * 256 + t;                       // 0..1023 chunks of [64][128]
    int row = idx >> 4, c8 = idx & 15;
    *(short8*)&sB[row * 136 + c8 * 8] = srcB[idx];
  }
  if (t < 128) sFam[t] = fam[R0 + t];
  __syncthreads();

  int w = t >> 6, lane = t & 63, m16 = lane & 15, q = lane >> 4;

  f32x4 acc[2][4] = {};
  const unsigned short* aB0 = &sA[(w * 32 + m16) * 136 + q * 8];
  const unsigned short* aB1 = aB0 + 16 * 136;
  const unsigned short* bB  = &sB[m16 * 136 + q * 8];

  #pragma unroll
  for (int ks = 0; ks < 4; ++ks) {
    int ko = ks * 32;
    short8 a0 = *(const short8*)(aB0 + ko);
    short8 a1 = *(const short8*)(aB1 + ko);
    short8 b0 = *(const short8*)(bB + ko);
    short8 b1 = *(const short8*)(bB + 16 * 136 + ko);
    short8 b2 = *(const short8*)(bB + 32 * 136 + ko);
    short8 b3 = *(const short8*)(bB + 48 * 136 + ko);
    acc[0][0] = __builtin_amdgcn_mfma_f32_16x16x32_bf16(a0, b0, acc[0][0], 0, 0, 0);
    acc[0][1] = __builtin_amdgcn_mfma_f32_16x16x32_bf16(a0, b1, acc[0][1], 0, 0, 0);
    acc[0][2] = __builtin_amdgcn_mfma_f32_16x16x32_bf16(a0, b2, acc[0][2], 0, 0, 0);
    acc[0][3] = __builtin_amdgcn_mfma_f32_16x16x32_bf16(a0, b3, acc[0][3], 0, 0, 0);
    acc[1][0] = __builtin_amdgcn_mfma_f32_16x16x32_bf16(a1, b0, acc[1][0], 0, 0, 0);
    acc[1][1] = __builtin_amdgcn_mfma_f32_16x16x32_bf16(a1, b1, acc[1][1], 0, 0, 0);
    acc[1][2] = __builtin_amdgcn_mfma_f32_16x16x32_bf16(a1, b2, acc[1][2], 0, 0, 0);
    acc[1][3] = __builtin_amdgcn_mfma_f32_16x16x32_bf16(a1, b3, acc[1][3], 0, 0, 0);
  }

  // epilogue: sim = acc. D[row=w*32+rt*16+q*4+i][col=ft*16+m16]=acc[rt][ft][i]
  // pos-term accumulated per-lane (m2ps); es reduced per q-group (4 shfls);
  // one full-wave reduce at the end.
  float wp = 0.f, m2ps = 0.f;
  #pragma unroll
  for (int rt = 0; rt < 2; ++rt) {
    #pragma unroll
    for (int i = 0; i < 4; ++i) {
      int row = w * 32 + rt * 16 + q * 4 + i;
      int fr = sFam[row], frh = fr >> 4, frl = fr & 15;
      float es = 0.f;
      #pragma unroll
      for (int ft = 0; ft < 4; ++ft) {
        float sim = acc[rt][ft][i];
        es += __expf(4.f * sim - 4.f);            // sim in [-1,1] -> arg [-8,0]
        if (frl == m16 && frh == ft) m2ps += sim;
      }
      es += __shfl_xor(es, 1);
      es += __shfl_xor(es, 2);
      es += __shfl_xor(es, 4);
      es += __shfl_xor(es, 8);
      if (m16 == 0) wp += 4.f + __logf(es);
    }
  }
  float tot = wp - 2.f * m2ps;
  tot += __shfl_xor(tot, 1);  tot += __shfl_xor(tot, 2);
  tot += __shfl_xor(tot, 4);  tot += __shfl_xor(tot, 8);
  tot += __shfl_xor(tot, 16); tot += __shfl_xor(tot, 32);
  if (lane == 0) sWp[w] = tot;
  __syncthreads();
  if (t == 0)
    unsafeAtomicAdd(out, (sWp[0] + sWp[1] + sWp[2] + sWp[3]) * invN);
}

extern "C" void kernel_launch(void* const* d_in, const int* in_sizes, int n_in,
                              void* d_out, int out_size, void* d_ws, size_t ws_size,
                              hipStream_t stream) {
  const float* emb = (const float*)d_in[0];
  const int* fam = (const int*)d_in[1];
  int N = in_sizes[0] / D_DIM;               // 262144
  int blocksA = N / 1024;                    // 256
  int blocksC = N / 128;                     // 2048

  // ws (float units): psum[256*8192] | protoB(8192 ushort) | ehat[N*64 uint]
  float* ws = (float*)d_ws;
  float* psum = ws;
  size_t off = (size_t)blocksA * (F_NUM * D_DIM);
  unsigned short* protoB = (unsigned short*)(ws + off); off += (F_NUM * D_DIM) / 2;
  unsigned int* ehat = (unsigned int*)(ws + off);

  (void)hipMemsetAsync(d_out, 0, sizeof(float), stream);
  pass_a<<<blocksA, 256, 0, stream>>>(emb, fam, psum, ehat);
  pass_b<<<F_NUM, 256, 0, stream>>>(psum, protoB, blocksA);
  pass_c<<<blocksC, 256, 0, stream>>>((const unsigned short*)ehat, fam, protoB,
                                      (float*)d_out, 1.0f / (float)N);
}